// Round 12
// baseline (41.071 us; speedup 1.0000x reference)
//
#include <hip/hip_runtime.h>
#include <math.h>

#define C_DIM 128
#define H_DIM 128
#define W_DIM 128
#define HW (H_DIM * W_DIM)
#define EPS_N 1e-12f
#define NT 512
#define NW 8        // waves per block
#define CPW 16      // channels per wave
#define LD2(p) (*(const float2*)(p))
#define LD4(p) (*(const float4*)(p))

// ---------------- kernel 1: reciprocal clamped L2 norm of fused over C ----------------
// float4 lanes: block covers 128 px; group g (8 groups) owns 16 channels.
__global__ __launch_bounds__(256) void norms_fu4(const float* __restrict__ fu,
                                                 float* __restrict__ rn)
{
    __shared__ float4 part[32][9];   // [lane][group], pad 9
    const int tid = threadIdx.x;
    const int li = tid & 31;
    const int g = tid >> 5;
    const float* p = fu + (size_t)blockIdx.y * C_DIM * HW + (size_t)g * 16 * HW
                     + blockIdx.x * 128 + 4 * li;
    float4 s = make_float4(0.f, 0.f, 0.f, 0.f);
#pragma unroll
    for (int j = 0; j < 16; ++j) {
        const float4 v = LD4(p + (size_t)j * HW);
        s.x += v.x * v.x; s.y += v.y * v.y;
        s.z += v.z * v.z; s.w += v.w * v.w;
    }
    part[li][g] = s;
    __syncthreads();
    if (tid < 32) {
        float4 t = make_float4(0.f, 0.f, 0.f, 0.f);
#pragma unroll
        for (int gg = 0; gg < 8; ++gg) {
            const float4 q = part[tid][gg];
            t.x += q.x; t.y += q.y; t.z += q.z; t.w += q.w;
        }
        float4 r;
        r.x = 1.f / fmaxf(sqrtf(t.x), EPS_N);
        r.y = 1.f / fmaxf(sqrtf(t.y), EPS_N);
        r.z = 1.f / fmaxf(sqrtf(t.z), EPS_N);
        r.w = 1.f / fmaxf(sqrtf(t.w), EPS_N);
        *(float4*)(rn + (size_t)blockIdx.y * HW + blockIdx.x * 128 + 4 * tid) = r;
    }
}

// ---------------- kernel 2: dots + softmax + aggregation ----------------
// R8-measured-passing compute, plus: explicit 2-deep register pipeline in both
// passes, and pass-2's first batch issued before the softmax barriers (T14).
__global__ __launch_bounds__(NT) void asfr_main3(const float* __restrict__ fe,
                                                 const float* __restrict__ fu,
                                                 const float* __restrict__ rn,
                                                 float* __restrict__ out)
{
    __shared__ float part[NW][10][W_DIM];  // 40 KB: [wave][9 dots + fe2][px]
    __shared__ float wl[9][W_DIM];         // 4.5 KB softmax weights
    __shared__ float n2r[3][W_DIM];        // 1.5 KB staged reciprocal fu norms

    const int tid = threadIdx.x;
    const int l   = tid & 63;
    const int wv  = tid >> 6;

    // XCD-chunked bijective swizzle (gridDim.x % 8 == 0)
    const int bid = blockIdx.x;
    const int cpx = gridDim.x >> 3;
    const int wb  = (bid & 7) * cpx + (bid >> 3);
    const int bz  = wb >> 7;
    const int row = wb & 127;

    const size_t imgbase = (size_t)bz * C_DIM * HW;
    const int c0   = wv * CPW;
    const int col0 = 2 * l;

    // stage n2r for rows row-1,row,row+1 (384 < NT=512)
    if (tid < 3 * W_DIM) {
        const int r = tid >> 7, c = tid & 127;
        const int nr = row + r - 1;
        float v = 1.f;
        if (nr >= 0 && nr < H_DIM) v = rn[(size_t)bz * HW + nr * W_DIM + c];
        n2r[r][c] = v;
    }

    const bool has_u = (row > 0), has_d = (row < H_DIM - 1);
    const int rup = has_u ? row - 1 : row;
    const int rdn = has_d ? row + 1 : row;

    const float* pfe = fe + imgbase + (size_t)c0 * HW + row * W_DIM + col0;
    const float* pfm = fu + imgbase + (size_t)c0 * HW + row * W_DIM + col0;
    const float* pfu = fu + imgbase + (size_t)c0 * HW + rup * W_DIM + col0;
    const float* pfd = fu + imgbase + (size_t)c0 * HW + rdn * W_DIM + col0;
    const float2 z2 = make_float2(0.f, 0.f);

    // batch loader (2 channels); OOB rows zeroed at load time
    auto ldpair = [&](int jb, float2& f0, float2& u0, float2& m0, float2& d0,
                      float2& f1, float2& u1, float2& m1, float2& d1) {
        const size_t oA = (size_t)(2 * jb) * HW;
        const size_t oB = oA + HW;
        f0 = LD2(pfe + oA); u0 = LD2(pfu + oA); m0 = LD2(pfm + oA); d0 = LD2(pfd + oA);
        f1 = LD2(pfe + oB); u1 = LD2(pfu + oB); m1 = LD2(pfm + oB); d1 = LD2(pfd + oB);
        if (!has_u) { u0 = z2; u1 = z2; }
        if (!has_d) { d0 = z2; d1 = z2; }
    };

    float2 dk[9];
#pragma unroll
    for (int k = 0; k < 9; ++k) dk[k] = z2;
    float2 fe2 = z2;

    auto acc3 = [&](const float2 f, const float2 v, const int r3) {
        float lft = __shfl_up(v.y, 1);   lft = (l == 0)  ? 0.f : lft;
        float rgt = __shfl_down(v.x, 1); rgt = (l == 63) ? 0.f : rgt;
        dk[r3+0].x += f.x * lft;  dk[r3+1].x += f.x * v.x;  dk[r3+2].x += f.x * v.y;
        dk[r3+0].y += f.y * v.x;  dk[r3+1].y += f.y * v.y;  dk[r3+2].y += f.y * rgt;
    };

    // ---------------- pass 1: 2-deep pipelined dots + ||fe||^2 ----------------
    {
        float2 fA, uA, mA, dA, fB, uB, mB, dB;
        ldpair(0, fA, uA, mA, dA, fB, uB, mB, dB);
#pragma unroll
        for (int jb = 0; jb < CPW / 2; ++jb) {
            float2 nfA, nuA, nmA, ndA, nfB, nuB, nmB, ndB;
            if (jb + 1 < CPW / 2)
                ldpair(jb + 1, nfA, nuA, nmA, ndA, nfB, nuB, nmB, ndB);
            fe2.x += fA.x * fA.x + fB.x * fB.x;
            fe2.y += fA.y * fA.y + fB.y * fB.y;
            acc3(fA, uA, 0); acc3(fA, mA, 3); acc3(fA, dA, 6);
            acc3(fB, uB, 0); acc3(fB, mB, 3); acc3(fB, dB, 6);
            if (jb + 1 < CPW / 2) {
                fA = nfA; uA = nuA; mA = nmA; dA = ndA;
                fB = nfB; uB = nuB; mB = nmB; dB = ndB;
            }
        }
    }

    // per-wave partials
#pragma unroll
    for (int k = 0; k < 9; ++k) *(float2*)&part[wv][k][col0] = dk[k];
    *(float2*)&part[wv][9][col0] = fe2;

    // T14: issue pass-2's first batch BEFORE the barriers; it flies during softmax
    float2 c2fA, c2uA, c2mA, c2dA, c2fB, c2uB, c2mB, c2dB;
    ldpair(0, c2fA, c2uA, c2mA, c2dA, c2fB, c2uB, c2mB, c2dB);
    __syncthreads();

    // ---------------- softmax (threads 0..127, one per pixel) ----------------
    if (tid < W_DIM) {
        const int px = tid;
        float dv[10];
#pragma unroll
        for (int k = 0; k < 10; ++k) {
            float s = 0.f;
#pragma unroll
            for (int w = 0; w < NW; ++w) s += part[w][k][px];
            dv[k] = s;
        }
        const float rfe = 1.f / fmaxf(sqrtf(dv[9]), EPS_N);
        float cs[9];
        float mx = -1e30f;
#pragma unroll
        for (int k = 0; k < 9; ++k) {
            const int di = k / 3, dj = k % 3;
            const int nr = row + di - 1;
            const int nc = px + dj - 1;
            const bool ok = (nr >= 0 && nr < H_DIM && nc >= 0 && nc < W_DIM);
            const int ncc = min(max(nc, 0), W_DIM - 1);
            const float cv = ok ? dv[k] * rfe * n2r[di][ncc] : 0.f;
            cs[k] = cv;
            mx = fmaxf(mx, cv);
        }
        float sum = 0.f;
#pragma unroll
        for (int k = 0; k < 9; ++k) { cs[k] = __expf(cs[k] - mx); sum += cs[k]; }
        const float is = 1.f / sum;
#pragma unroll
        for (int k = 0; k < 9; ++k) wl[k][px] = cs[k] * is;
    }
    __syncthreads();

    // ---------------- pass 2: 2-deep pipelined aggregation + residual ----------------
    float2 w2[9];
#pragma unroll
    for (int k = 0; k < 9; ++k) w2[k] = *(const float2*)&wl[k][col0];

    auto agg3 = [&](float2& acc, const float2 w9[9], const float2 v, const int r3) {
        float lft = __shfl_up(v.y, 1);   lft = (l == 0)  ? 0.f : lft;
        float rgt = __shfl_down(v.x, 1); rgt = (l == 63) ? 0.f : rgt;
        acc.x += w9[r3+0].x * lft  + w9[r3+1].x * v.x + w9[r3+2].x * v.y;
        acc.y += w9[r3+0].y * v.x  + w9[r3+1].y * v.y + w9[r3+2].y * rgt;
    };

    float* pout = out + imgbase + (size_t)c0 * HW + row * W_DIM + col0;
#pragma unroll
    for (int jb = 0; jb < CPW / 2; ++jb) {
        float2 nfA, nuA, nmA, ndA, nfB, nuB, nmB, ndB;
        if (jb + 1 < CPW / 2)
            ldpair(jb + 1, nfA, nuA, nmA, ndA, nfB, nuB, nmB, ndB);
        float2 accA = c2fA;   // residual
        float2 accB = c2fB;
        agg3(accA, w2, c2uA, 0); agg3(accA, w2, c2mA, 3); agg3(accA, w2, c2dA, 6);
        agg3(accB, w2, c2uB, 0); agg3(accB, w2, c2mB, 3); agg3(accB, w2, c2dB, 6);
        const size_t oA = (size_t)(2 * jb) * HW;
        *(float2*)(pout + oA)      = accA;
        *(float2*)(pout + oA + HW) = accB;
        if (jb + 1 < CPW / 2) {
            c2fA = nfA; c2uA = nuA; c2mA = nmA; c2dA = ndA;
            c2fB = nfB; c2uB = nuB; c2mB = nmB; c2dB = ndB;
        }
    }
}

extern "C" void kernel_launch(void* const* d_in, const int* in_sizes, int n_in,
                              void* d_out, int out_size, void* d_ws, size_t ws_size,
                              hipStream_t stream) {
    const float* fe = (const float*)d_in[0];   // fe_lv
    const float* fu = (const float*)d_in[1];   // fused_features
    float* out = (float*)d_out;
    float* rn = (float*)d_ws;                  // B*HW floats
    const int B = in_sizes[0] / (C_DIM * HW);

    dim3 g1(HW / 128, B);
    norms_fu4<<<g1, 256, 0, stream>>>(fu, rn);

    dim3 g2(B * H_DIM);
    asfr_main3<<<g2, NT, 0, stream>>>(fe, fu, rn, out);
}

// Round 13
// 38.295 us; speedup vs baseline: 1.0725x; 1.0725x over previous
//
#include <hip/hip_runtime.h>
#include <math.h>

#define C_DIM 128
#define H_DIM 128
#define W_DIM 128
#define HW (H_DIM * W_DIM)
#define EPS_N 1e-12f
#define NSL 4                   // channel slices (K2) / channel groups (K3)
#define CPS (C_DIM / NSL)       // 32 channels per slice
#define CPWV 8                  // channels per wave (4 waves x 8 = 32)
#define NPL 11                  // planes per (row,slice): 9 dots + fe2 + norm2
#define PS (NPL * W_DIM)        // 1408 floats per (row,slice)
#define LD2(p) (*(const float2*)(p))

// ---------------- K2: per-slice partial dots + fe2 + own-row fu-norm^2 ----------------
// Block = (row, slice): 256 thr = 4 waves x 8 channels; lane l owns px 2l,2l+1.
// Writes part[RG][slice][11][128] to d_ws. R8-measured acc3 compute, verbatim.
__global__ __launch_bounds__(256) void k2_partial(const float* __restrict__ fe,
                                                  const float* __restrict__ fu,
                                                  float* __restrict__ pg)
{
    __shared__ float pl[4][PS];   // 22.5 KB per-wave partial slots

    const int tid = threadIdx.x;
    const int l   = tid & 63;
    const int wv  = tid >> 6;

    // XCD-chunked bijective swizzle (gridDim.x = 4*B*H, % 8 == 0)
    const int bid = blockIdx.x;
    const int cpx = gridDim.x >> 3;
    const int wb  = (bid & 7) * cpx + (bid >> 3);
    const int slice = wb & (NSL - 1);
    const int RG  = wb >> 2;          // global row index (bz*128 + row)
    const int bz  = RG >> 7;
    const int row = RG & 127;

    const size_t imgbase = (size_t)bz * C_DIM * HW;
    const int c0   = slice * CPS + wv * CPWV;
    const int col0 = 2 * l;

    const bool has_u = (row > 0), has_d = (row < H_DIM - 1);
    const int rup = has_u ? row - 1 : row;
    const int rdn = has_d ? row + 1 : row;

    const float* pfe = fe + imgbase + (size_t)c0 * HW + row * W_DIM + col0;
    const float* pfm = fu + imgbase + (size_t)c0 * HW + row * W_DIM + col0;
    const float* pfu = fu + imgbase + (size_t)c0 * HW + rup * W_DIM + col0;
    const float* pfd = fu + imgbase + (size_t)c0 * HW + rdn * W_DIM + col0;
    const float2 z2 = make_float2(0.f, 0.f);

    float2 dk[9];
#pragma unroll
    for (int k = 0; k < 9; ++k) dk[k] = z2;
    float2 fe2 = z2, s2 = z2;

    auto acc3 = [&](const float2 f, const float2 v, const int r3) {
        float lft = __shfl_up(v.y, 1);   lft = (l == 0)  ? 0.f : lft;
        float rgt = __shfl_down(v.x, 1); rgt = (l == 63) ? 0.f : rgt;
        dk[r3+0].x += f.x * lft;  dk[r3+1].x += f.x * v.x;  dk[r3+2].x += f.x * v.y;
        dk[r3+0].y += f.y * v.x;  dk[r3+1].y += f.y * v.y;  dk[r3+2].y += f.y * rgt;
    };

#pragma unroll
    for (int j = 0; j < CPWV; ++j) {
        const size_t off = (size_t)j * HW;
        float2 f = LD2(pfe + off);
        float2 u = LD2(pfu + off);
        float2 m = LD2(pfm + off);
        float2 d = LD2(pfd + off);
        if (!has_u) u = z2;
        if (!has_d) d = z2;
        fe2.x += f.x * f.x; fe2.y += f.y * f.y;
        s2.x  += m.x * m.x; s2.y  += m.y * m.y;
        acc3(f, u, 0); acc3(f, m, 3); acc3(f, d, 6);
    }

#pragma unroll
    for (int k = 0; k < 9; ++k) *(float2*)&pl[wv][k * W_DIM + col0] = dk[k];
    *(float2*)&pl[wv][9 * W_DIM + col0]  = fe2;
    *(float2*)&pl[wv][10 * W_DIM + col0] = s2;
    __syncthreads();

    // reduce the 4 wave slots and stream to global partials
    float* dst = pg + ((size_t)RG * NSL + slice) * PS;
    for (int t = tid; t < PS; t += 256)
        dst[t] = pl[0][t] + pl[1][t] + pl[2][t] + pl[3][t];
}

// ---------------- K3: softmax (from partials) + aggregation + residual ----------------
// Block = (row, channel-group): 256 thr = 4 waves x 8 channels. Each block
// redundantly computes its row's softmax from the 4 slice-partials (L2-hot,
// ~6 KB), then aggregates its 32 channels. R8-measured softmax/agg3 verbatim.
__global__ __launch_bounds__(256) void k3_agg(const float* __restrict__ fe,
                                              const float* __restrict__ fu,
                                              const float* __restrict__ pg,
                                              float* __restrict__ out)
{
    __shared__ float dvs[10 * W_DIM];   // summed dot planes + fe2
    __shared__ float n2r[3 * W_DIM];    // reciprocal neighbor-row fu norms
    __shared__ float wl[9][W_DIM];      // softmax weights

    const int tid = threadIdx.x;
    const int l   = tid & 63;
    const int wv  = tid >> 6;

    const int bid = blockIdx.x;
    const int cpx = gridDim.x >> 3;
    const int wb  = (bid & 7) * cpx + (bid >> 3);
    const int cg  = wb & (NSL - 1);
    const int RG  = wb >> 2;
    const int bz  = RG >> 7;
    const int row = RG & 127;

    // sum the 4 slices' dot/fe2 planes for this row
    {
        const float* src = pg + (size_t)RG * NSL * PS;
        for (int t = tid; t < 10 * W_DIM; t += 256)
            dvs[t] = src[t] + src[PS + t] + src[2 * PS + t] + src[3 * PS + t];
    }
    // neighbor-row norms from the norm2 planes (clamped rows; masked in softmax)
    for (int t = tid; t < 3 * W_DIM; t += 256) {
        const int r = t >> 7, c = t & 127;
        const int nrc = min(max(row + r - 1, 0), H_DIM - 1);
        const float* nb = pg + ((size_t)(bz * H_DIM + nrc) * NSL) * PS + 10 * W_DIM;
        const float s = nb[c] + nb[PS + c] + nb[2 * PS + c] + nb[3 * PS + c];
        n2r[t] = 1.f / fmaxf(sqrtf(s), EPS_N);
    }
    __syncthreads();

    // softmax (threads 0..127, one per pixel)
    if (tid < W_DIM) {
        const int px = tid;
        const float rfe = 1.f / fmaxf(sqrtf(dvs[9 * W_DIM + px]), EPS_N);
        float cs[9];
        float mx = -1e30f;
#pragma unroll
        for (int k = 0; k < 9; ++k) {
            const int di = k / 3, dj = k % 3;
            const int nr = row + di - 1;
            const int nc = px + dj - 1;
            const bool ok = (nr >= 0 && nr < H_DIM && nc >= 0 && nc < W_DIM);
            const int ncc = min(max(nc, 0), W_DIM - 1);
            const float cv = ok ? dvs[k * W_DIM + px] * rfe * n2r[di * W_DIM + ncc] : 0.f;
            cs[k] = cv;
            mx = fmaxf(mx, cv);
        }
        float sum = 0.f;
#pragma unroll
        for (int k = 0; k < 9; ++k) { cs[k] = __expf(cs[k] - mx); sum += cs[k]; }
        const float is = 1.f / sum;
#pragma unroll
        for (int k = 0; k < 9; ++k) wl[k][px] = cs[k] * is;
    }
    __syncthreads();

    // aggregation for this block's 32 channels
    const size_t imgbase = (size_t)bz * C_DIM * HW;
    const int c0   = cg * CPS + wv * CPWV;
    const int col0 = 2 * l;
    const bool has_u = (row > 0), has_d = (row < H_DIM - 1);
    const int rup = has_u ? row - 1 : row;
    const int rdn = has_d ? row + 1 : row;

    const float* pfe = fe + imgbase + (size_t)c0 * HW + row * W_DIM + col0;
    const float* pfm = fu + imgbase + (size_t)c0 * HW + row * W_DIM + col0;
    const float* pfu = fu + imgbase + (size_t)c0 * HW + rup * W_DIM + col0;
    const float* pfd = fu + imgbase + (size_t)c0 * HW + rdn * W_DIM + col0;
    float* pout = out + imgbase + (size_t)c0 * HW + row * W_DIM + col0;
    const float2 z2 = make_float2(0.f, 0.f);

    float2 w2[9];
#pragma unroll
    for (int k = 0; k < 9; ++k) w2[k] = *(const float2*)&wl[k][col0];

    auto agg3 = [&](float2& acc, const float2 v, const int r3) {
        float lft = __shfl_up(v.y, 1);   lft = (l == 0)  ? 0.f : lft;
        float rgt = __shfl_down(v.x, 1); rgt = (l == 63) ? 0.f : rgt;
        acc.x += w2[r3+0].x * lft  + w2[r3+1].x * v.x + w2[r3+2].x * v.y;
        acc.y += w2[r3+0].y * v.x  + w2[r3+1].y * v.y + w2[r3+2].y * rgt;
    };

#pragma unroll
    for (int j = 0; j < CPWV; ++j) {
        const size_t off = (size_t)j * HW;
        float2 f = LD2(pfe + off);
        float2 u = LD2(pfu + off);
        float2 m = LD2(pfm + off);
        float2 d = LD2(pfd + off);
        if (!has_u) u = z2;
        if (!has_d) d = z2;
        float2 acc = f;   // residual
        agg3(acc, u, 0); agg3(acc, m, 3); agg3(acc, d, 6);
        *(float2*)(pout + off) = acc;
    }
}

extern "C" void kernel_launch(void* const* d_in, const int* in_sizes, int n_in,
                              void* d_out, int out_size, void* d_ws, size_t ws_size,
                              hipStream_t stream) {
    const float* fe = (const float*)d_in[0];   // fe_lv
    const float* fu = (const float*)d_in[1];   // fused_features
    float* out = (float*)d_out;
    float* pg = (float*)d_ws;                  // B*H*4*1408 floats (11.5 MB @ B=4)
    const int B = in_sizes[0] / (C_DIM * HW);

    dim3 g(B * H_DIM * NSL);                   // 2048 blocks @ B=4
    k2_partial<<<g, 256, 0, stream>>>(fe, fu, pg);
    k3_agg<<<g, 256, 0, stream>>>(fe, fu, pg, out);
}